// Round 1
// baseline (1051.276 us; speedup 1.0000x reference)
//
#include <hip/hip_runtime.h>
#include <hip/hip_bf16.h>
#include <math.h>

typedef float f32x4 __attribute__((ext_vector_type(4)));
typedef __bf16 bf16x8 __attribute__((ext_vector_type(8)));
typedef unsigned short u16x8 __attribute__((ext_vector_type(8)));
typedef unsigned short u16x4 __attribute__((ext_vector_type(4)));

__device__ __forceinline__ float bf2f(unsigned short u) {
    unsigned int x = ((unsigned int)u) << 16;
    float f; __builtin_memcpy(&f, &x, 4); return f;
}
__device__ __forceinline__ unsigned short f2bf(float f) {
    unsigned int x; __builtin_memcpy(&x, &f, 4);
    unsigned int r = x + 0x7fffu + ((x >> 16) & 1u);
    return (unsigned short)(r >> 16);
}
__device__ __forceinline__ float gelu_exact(float v) {
    return 0.5f * v * (1.0f + erff(v * 0.70710678118654752f));
}

// ---------------------------------------------------------------------------
// Weight transpose: fp32 [K][N] -> bf16 [N][K]
// ---------------------------------------------------------------------------
__global__ __launch_bounds__(256) void transpose_w(
    const float* __restrict__ in, unsigned short* __restrict__ out, int K, int N)
{
    __shared__ unsigned short tile[64][72];
    int nbn = N >> 6;
    int tk = (blockIdx.x / nbn) << 6;
    int tn = (blockIdx.x % nbn) << 6;
    int t = threadIdx.x;
    int r = t >> 2, c0 = (t & 3) * 16;
    #pragma unroll
    for (int i = 0; i < 16; i += 4) {
        float4 f = *(const float4*)(in + (size_t)(tk + r) * N + tn + c0 + i);
        tile[r][c0 + i + 0] = f2bf(f.x);
        tile[r][c0 + i + 1] = f2bf(f.y);
        tile[r][c0 + i + 2] = f2bf(f.z);
        tile[r][c0 + i + 3] = f2bf(f.w);
    }
    __syncthreads();
    u16x8 o0, o1;
    #pragma unroll
    for (int i = 0; i < 8; i++) { o0[i] = tile[c0 + i][r]; o1[i] = tile[c0 + 8 + i][r]; }
    *(u16x8*)(out + (size_t)(tn + r) * K + tk + c0)     = o0;
    *(u16x8*)(out + (size_t)(tn + r) * K + tk + c0 + 8) = o1;
}

// ---------------------------------------------------------------------------
// LayerNorm fp32 [rows][1024] -> bf16, gamma/beta applied
// ---------------------------------------------------------------------------
__global__ __launch_bounds__(256) void ln_kernel(
    const float* __restrict__ x, const float* __restrict__ gamma,
    const float* __restrict__ beta, unsigned short* __restrict__ out)
{
    int row = blockIdx.x;
    int t = threadIdx.x;
    float4 v = ((const float4*)(x + (size_t)row * 1024))[t];
    float s  = v.x + v.y + v.z + v.w;
    float s2 = v.x * v.x + v.y * v.y + v.z * v.z + v.w * v.w;
    #pragma unroll
    for (int o = 32; o > 0; o >>= 1) { s += __shfl_down(s, o); s2 += __shfl_down(s2, o); }
    __shared__ float red[8];
    if ((t & 63) == 0) { red[t >> 6] = s; red[4 + (t >> 6)] = s2; }
    __syncthreads();
    s  = red[0] + red[1] + red[2] + red[3];
    s2 = red[4] + red[5] + red[6] + red[7];
    float mu  = s * (1.0f / 1024.0f);
    float var = s2 * (1.0f / 1024.0f) - mu * mu;
    float rs  = rsqrtf(var + 1e-6f);
    float4 g  = ((const float4*)gamma)[t];
    float4 be = ((const float4*)beta)[t];
    u16x4 o4;
    o4[0] = f2bf((v.x - mu) * rs * g.x + be.x);
    o4[1] = f2bf((v.y - mu) * rs * g.y + be.y);
    o4[2] = f2bf((v.z - mu) * rs * g.z + be.z);
    o4[3] = f2bf((v.w - mu) * rs * g.w + be.w);
    *(u16x4*)(out + (size_t)row * 1024 + t * 4) = o4;
}

// ---------------------------------------------------------------------------
// GEMM: C[M][N] = A[M][K](bf16) * Bt[N][K](bf16)^T  with fused epilogues
// EP: 0 = store bf16 | 1 = relu+1e-3 bf16 | 2 = +addv f32
//     3 = +bias, gelu, bf16 | 4 = +bias, gelu, +addv, f32
// Tile 128x128, BK=64, 256 threads = 4 waves (2x2 of 64x64).
// ---------------------------------------------------------------------------
template <int EP>
__global__ __launch_bounds__(256) void gemm_bt(
    const unsigned short* __restrict__ A, const unsigned short* __restrict__ Bt,
    void* __restrict__ C, const float* __restrict__ bias,
    const float* __restrict__ addv, int M, int N, int K)
{
    __shared__ unsigned short Al[128 * 64];
    __shared__ unsigned short Bl[128 * 64];
    int nbn = N >> 7;
    int tm = blockIdx.x / nbn, tn = blockIdx.x % nbn;
    const int tid = threadIdx.x;
    const int lane = tid & 63, wid = tid >> 6;
    const int l15 = lane & 15, l4 = lane >> 4;
    const int wr = wid >> 1, wc = wid & 1;
    f32x4 acc[4][4] = {};
    const unsigned short* Ab = A + (size_t)(tm * 128) * K;
    const unsigned short* Bb = Bt + (size_t)(tn * 128) * K;

    for (int k0 = 0; k0 < K; k0 += 64) {
        #pragma unroll
        for (int i = 0; i < 4; i++) {
            int chunk = tid + i * 256;
            int row = chunk >> 3, c = (chunk & 7) * 8;
            u16x8 av = *(const u16x8*)(Ab + (size_t)row * K + k0 + c);
            u16x8 bv = *(const u16x8*)(Bb + (size_t)row * K + k0 + c);
            int off = (row * 128 + c * 2) ^ ((row & 7) << 4);
            *(u16x8*)((char*)Al + off) = av;
            *(u16x8*)((char*)Bl + off) = bv;
        }
        __syncthreads();
        #pragma unroll
        for (int kk = 0; kk < 64; kk += 32) {
            bf16x8 af[4], bfr[4];
            #pragma unroll
            for (int m = 0; m < 4; m++) {
                int row = wr * 64 + m * 16 + l15;
                int off = (row * 128 + (kk + l4 * 8) * 2) ^ ((row & 7) << 4);
                af[m] = *(const bf16x8*)((const char*)Al + off);
            }
            #pragma unroll
            for (int n = 0; n < 4; n++) {
                int row = wc * 64 + n * 16 + l15;
                int off = (row * 128 + (kk + l4 * 8) * 2) ^ ((row & 7) << 4);
                bfr[n] = *(const bf16x8*)((const char*)Bl + off);
            }
            #pragma unroll
            for (int m = 0; m < 4; m++)
                #pragma unroll
                for (int n = 0; n < 4; n++)
                    acc[m][n] = __builtin_amdgcn_mfma_f32_16x16x32_bf16(af[m], bfr[n], acc[m][n], 0, 0, 0);
        }
        __syncthreads();
    }

    int rbase = tm * 128 + wr * 64;
    int cbase = tn * 128 + wc * 64;
    #pragma unroll
    for (int m = 0; m < 4; m++) {
        #pragma unroll
        for (int n = 0; n < 4; n++) {
            int col = cbase + n * 16 + l15;
            float bval = 0.f;
            if constexpr (EP == 3 || EP == 4) bval = bias[col];
            #pragma unroll
            for (int j = 0; j < 4; j++) {
                int row = rbase + m * 16 + l4 * 4 + j;
                float val = acc[m][n][j];
                if constexpr (EP == 1) val = fmaxf(val, 0.f) + 1e-3f;
                if constexpr (EP == 3 || EP == 4) val = gelu_exact(val + bval);
                if constexpr (EP == 0 || EP == 1 || EP == 3) {
                    ((unsigned short*)C)[(size_t)row * N + col] = f2bf(val);
                } else {
                    ((float*)C)[(size_t)row * N + col] = val + addv[(size_t)row * N + col];
                }
            }
        }
    }
}

// ---------------------------------------------------------------------------
// kvs / ksum: kvsT[b][h][d][m] = sum_l kp[b,l,h,m]*v[b,l,h,d]; ksum[b][h][m]
// grid = B*H*8 (L split 8 ways, 256 rows each), atomic accumulate (fp32)
// ---------------------------------------------------------------------------
__global__ __launch_bounds__(256) void kvs_kernel(
    const unsigned short* __restrict__ kp, const unsigned short* __restrict__ v,
    float* __restrict__ kvsT, float* __restrict__ ksum)
{
    int blk = blockIdx.x;
    int sp = blk & 7, h = (blk >> 3) & 15, b = blk >> 7;
    int l0 = sp * 256;
    const unsigned short* kpb = kp + ((size_t)(b * 2048 + l0)) * 1024 + h * 64;
    const unsigned short* vb  = v  + ((size_t)(b * 2048 + l0)) * 1024 + h * 64;
    __shared__ unsigned short kl[32][64];
    __shared__ unsigned short vl[32][64];
    int t = threadIdx.x;
    int d = t & 63, mb = (t >> 6) * 16;
    float acc[16] = {};
    float ks0 = 0.f;
    for (int lc = 0; lc < 256; lc += 32) {
        int row = t >> 3, c = (t & 7) * 8;
        *(u16x8*)&kl[row][c] = *(const u16x8*)(kpb + (size_t)(lc + row) * 1024 + c);
        *(u16x8*)&vl[row][c] = *(const u16x8*)(vb  + (size_t)(lc + row) * 1024 + c);
        __syncthreads();
        for (int l = 0; l < 32; l++) {
            float vv = bf2f(vl[l][d]);
            u16x8 k0 = *(const u16x8*)&kl[l][mb];
            u16x8 k1 = *(const u16x8*)&kl[l][mb + 8];
            #pragma unroll
            for (int q = 0; q < 8; q++) {
                acc[q]     += bf2f(k0[q]) * vv;
                acc[8 + q] += bf2f(k1[q]) * vv;
            }
        }
        if (t < 64) {
            #pragma unroll
            for (int l = 0; l < 32; l++) ks0 += bf2f(kl[l][t]);
        }
        __syncthreads();
    }
    float* kvb = kvsT + ((size_t)(b * 16 + h) * 64 + d) * 64 + mb;
    #pragma unroll
    for (int q = 0; q < 16; q++) atomicAdd(&kvb[q], acc[q]);
    if (t < 64) atomicAdd(&ksum[(b * 16 + h) * 64 + t], ks0);
}

// ---------------------------------------------------------------------------
// att = (qp @ kvs) / (qp @ ksum), per (b,h), 128-row tiles, written IN PLACE
// over qp (block reads its slice into LDS before writing).
// grid = B*H*16; A = qp tile [128][64], B = kvsT[b][h] (fp32 -> bf16)
// ---------------------------------------------------------------------------
__global__ __launch_bounds__(256) void att_num_kernel(
    const unsigned short* __restrict__ qp, const float* __restrict__ kvsT,
    const float* __restrict__ ksum, unsigned short* __restrict__ att)
{
    int blk = blockIdx.x;
    int t16 = blk & 15, h = (blk >> 4) & 15, b = blk >> 8;
    __shared__ unsigned short Al[128 * 64];
    __shared__ unsigned short Bl[64 * 64];
    __shared__ float kss[64];
    int tid = threadIdx.x;
    int lane = tid & 63, wid = tid >> 6;
    int l15 = lane & 15, l4 = lane >> 4;
    const unsigned short* Ab = qp + ((size_t)(b * 2048 + t16 * 128)) * 1024 + h * 64;
    const float* Bb  = kvsT + (size_t)(b * 16 + h) * 4096;
    const float* ksb = ksum + (b * 16 + h) * 64;
    #pragma unroll
    for (int i = 0; i < 4; i++) {
        int chunk = tid + i * 256;
        int row = chunk >> 3, c = (chunk & 7) * 8;
        u16x8 av = *(const u16x8*)(Ab + (size_t)row * 1024 + c);
        int off = (row * 128 + c * 2) ^ ((row & 7) << 4);
        *(u16x8*)((char*)Al + off) = av;
    }
    #pragma unroll
    for (int i = 0; i < 2; i++) {
        int chunk = tid + i * 256;
        int row = chunk >> 3, c = (chunk & 7) * 8;
        const float* src = Bb + (size_t)row * 64 + c;
        u16x8 bv;
        #pragma unroll
        for (int q = 0; q < 8; q++) bv[q] = f2bf(src[q]);
        int off = (row * 128 + c * 2) ^ ((row & 7) << 4);
        *(u16x8*)((char*)Bl + off) = bv;
    }
    if (tid < 64) kss[tid] = ksb[tid];
    __syncthreads();

    f32x4 acc[2][4] = {};
    #pragma unroll
    for (int kk = 0; kk < 64; kk += 32) {
        bf16x8 af[2], bfr[4];
        #pragma unroll
        for (int m = 0; m < 2; m++) {
            int row = wid * 32 + m * 16 + l15;
            int off = (row * 128 + (kk + l4 * 8) * 2) ^ ((row & 7) << 4);
            af[m] = *(const bf16x8*)((const char*)Al + off);
        }
        #pragma unroll
        for (int n = 0; n < 4; n++) {
            int row = n * 16 + l15;
            int off = (row * 128 + (kk + l4 * 8) * 2) ^ ((row & 7) << 4);
            bfr[n] = *(const bf16x8*)((const char*)Bl + off);
        }
        #pragma unroll
        for (int m = 0; m < 2; m++)
            #pragma unroll
            for (int n = 0; n < 4; n++)
                acc[m][n] = __builtin_amdgcn_mfma_f32_16x16x32_bf16(af[m], bfr[n], acc[m][n], 0, 0, 0);
    }
    __syncthreads();  // everyone done reading Al before in-place writes land

    #pragma unroll
    for (int m = 0; m < 2; m++) {
        #pragma unroll
        for (int j = 0; j < 4; j++) {
            int lrow = wid * 32 + m * 16 + l4 * 4 + j;
            float den = 0.f;
            #pragma unroll
            for (int mm = 0; mm < 64; mm += 8) {
                int off = (lrow * 128 + mm * 2) ^ ((lrow & 7) << 4);
                u16x8 a8 = *(const u16x8*)((const char*)Al + off);
                #pragma unroll
                for (int q = 0; q < 8; q++) den += bf2f(a8[q]) * kss[mm + q];
            }
            float rden = 1.0f / den;
            size_t grow = (size_t)(b * 2048 + t16 * 128 + lrow);
            #pragma unroll
            for (int n = 0; n < 4; n++) {
                int col = h * 64 + n * 16 + l15;
                att[grow * 1024 + col] = f2bf(acc[m][n][j] * rden);
            }
        }
    }
}

// ---------------------------------------------------------------------------
extern "C" void kernel_launch(void* const* d_in, const int* in_sizes, int n_in,
                              void* d_out, int out_size, void* d_ws, size_t ws_size,
                              hipStream_t stream) {
    (void)in_sizes; (void)n_in; (void)out_size; (void)ws_size;
    const float* x      = (const float*)d_in[0];
    const float* gamma1 = (const float*)d_in[1];
    const float* beta1  = (const float*)d_in[2];
    const float* wq     = (const float*)d_in[3];
    const float* wk     = (const float*)d_in[4];
    const float* wv     = (const float*)d_in[5];
    const float* wo     = (const float*)d_in[6];
    const float* w1     = (const float*)d_in[7];
    const float* b1     = (const float*)d_in[8];
    const float* w2     = (const float*)d_in[9];
    const float* b2     = (const float*)d_in[10];
    float* out = (float*)d_out;

    const size_t MB = 1024 * 1024;
    char* ws = (char*)d_ws;
    unsigned short* wq_bt = (unsigned short*)(ws + 0 * MB);
    unsigned short* wk_bt = (unsigned short*)(ws + 2 * MB);
    unsigned short* wv_bt = (unsigned short*)(ws + 4 * MB);
    unsigned short* wo_bt = (unsigned short*)(ws + 6 * MB);
    unsigned short* w1_bt = (unsigned short*)(ws + 8 * MB);
    unsigned short* w2_bt = (unsigned short*)(ws + 16 * MB);
    unsigned short* lnbuf = (unsigned short*)(ws + 24 * MB);   // 32 MB (ln1 then ln2)
    float*          add1  = (float*)(ws + 56 * MB);            // 64 MB fp32
    unsigned short* qp    = (unsigned short*)(ws + 120 * MB);  // 32 MB (att in-place later)
    unsigned short* kp    = (unsigned short*)(ws + 152 * MB);  // 32 MB
    unsigned short* vb    = (unsigned short*)(ws + 184 * MB);  // 32 MB
    float*          kvsT  = (float*)(ws + 216 * MB);           // 2 MB
    float*          ksum  = (float*)(ws + 218 * MB);           // 32 KB
    unsigned short* hbuf  = (unsigned short*)(ws + 120 * MB);  // 128 MB, reuses qp..kvsT region

    dim3 blk(256);
    // weights -> bf16 transposed [N][K]
    transpose_w<<<dim3(256),  blk, 0, stream>>>(wq, wq_bt, 1024, 1024);
    transpose_w<<<dim3(256),  blk, 0, stream>>>(wk, wk_bt, 1024, 1024);
    transpose_w<<<dim3(256),  blk, 0, stream>>>(wv, wv_bt, 1024, 1024);
    transpose_w<<<dim3(256),  blk, 0, stream>>>(wo, wo_bt, 1024, 1024);
    transpose_w<<<dim3(1024), blk, 0, stream>>>(w1, w1_bt, 1024, 4096);
    transpose_w<<<dim3(1024), blk, 0, stream>>>(w2, w2_bt, 4096, 1024);
    // ln1
    ln_kernel<<<dim3(16384), blk, 0, stream>>>(x, gamma1, beta1, lnbuf);
    // q,k,v projections (relu+stab fused for q,k)
    gemm_bt<1><<<dim3(1024), blk, 0, stream>>>(lnbuf, wq_bt, qp, nullptr, nullptr, 16384, 1024, 1024);
    gemm_bt<1><<<dim3(1024), blk, 0, stream>>>(lnbuf, wk_bt, kp, nullptr, nullptr, 16384, 1024, 1024);
    gemm_bt<0><<<dim3(1024), blk, 0, stream>>>(lnbuf, wv_bt, vb, nullptr, nullptr, 16384, 1024, 1024);
    // kvs + ksum
    hipMemsetAsync(kvsT, 0, 2 * MB + 32 * 1024, stream);
    kvs_kernel<<<dim3(1024), blk, 0, stream>>>(kp, vb, kvsT, ksum);
    // att = (qp@kvs)/(qp@ksum), in place over qp
    att_num_kernel<<<dim3(2048), blk, 0, stream>>>(qp, kvsT, ksum, qp);
    // attn_out = att @ wo, + x -> add1 (fp32)
    gemm_bt<2><<<dim3(1024), blk, 0, stream>>>(qp, wo_bt, add1, nullptr, x, 16384, 1024, 1024);
    // ln2 (reference reuses gamma1/beta1)
    ln_kernel<<<dim3(16384), blk, 0, stream>>>(add1, gamma1, beta1, lnbuf);
    // FFN
    gemm_bt<3><<<dim3(4096), blk, 0, stream>>>(lnbuf, w1_bt, hbuf, b1, nullptr, 16384, 4096, 1024);
    gemm_bt<4><<<dim3(1024), blk, 0, stream>>>(hbuf, w2_bt, out, b2, add1, 16384, 1024, 4096);
}